// Round 9
// baseline (154.394 us; speedup 1.0000x reference)
//
#include <hip/hip_runtime.h>

typedef unsigned short u16;
typedef __attribute__((ext_vector_type(8))) short short8;
typedef __attribute__((ext_vector_type(4))) float f32x4;

#define NF 2
#define NV 4
#define FV 8
#define NE 2048
#define NIN 512
#define NOUT 512
#define NM 514

// ws layout (bytes)
#define WS_P1      0u         // 64 slots, stride 8 floats (32B)
#define WS_P2      2048u      // 32 slots * 32B
#define WS_P3      3072u      // 32 slots
#define WS_CTR     4096u      // gemm completion counter (4B, pad to 128)
#define WS_SCALE   4224u      // 512 f
#define WS_G       6272u      // 514 f (pad 2176)
#define WS_GN      8448u      // 512 f
#define WS_ETA     10496u     // 512 float4
#define WS_BIASZ   18688u     // 8*512 f (RAW th row 512)
#define WS_BIAST   35072u     // 8*512 f (RAW sign*gi row 512)
#define WS_DENP    51456u     // 8mt*8fv*512 f = 131072
#define WS_PMIN    182528u    // 64*512 f
#define WS_PSUM    313600u
#define WS_ABF     444672u    // 8*2048*512 u16
#define WS_BZT     17221888u  // 8*512*512 u16
#define WS_BTT     21416192u  // -> end 25610496

__constant__ float c_etas[4][4] = {
    {0.05f, 0.90f, 0.20f, 8.0f},
    {0.10f, 0.80f, 0.30f, 5.0f},
    {0.00f, 1.00f, 0.25f, 10.0f},
    {0.15f, 0.70f, 0.15f, 6.0f}};

__device__ __forceinline__ u16 f2bf(float x) {
    unsigned u = __float_as_uint(x);
    unsigned r = (u + 0x7fffu + ((u >> 16) & 1u)) >> 16;
    return (u16)r;
}

__device__ __forceinline__ void gll16(const void* g, void* l) {
    __builtin_amdgcn_global_load_lds((__attribute__((address_space(1))) void*)g,
                                     (__attribute__((address_space(3))) void*)l,
                                     16, 0, 0);
}

// ---- kA: per-column partial min/sum of g_init; block 0 zeroes slots+ctr ----
__global__ void kA_part(const float* __restrict__ theta_, float* __restrict__ pmin,
                        float* __restrict__ psum, float* __restrict__ wszero) {
    int t = threadIdx.x;
    if (blockIdx.x == 0) {
        // zero p1/p2/p3 slots + ctr: bytes [0, 4224) = 1056 floats
        for (int i = t; i < 1056; i += 256) wszero[i] = 0.f;
    }
    int n2 = t * 2;
    int r0 = blockIdx.x * 9;
    float mn0 = 3.4e38f, mn1 = 3.4e38f, s0 = 0.f, s1 = 0.f;
    int rend = r0 + 9;
    if (rend > NM) rend = NM;
    for (int r = r0; r < rend; r++) {
        float2 v = *(const float2*)(theta_ + r * NOUT + n2);
        float a0 = fabsf(fminf(fmaxf(v.x, -10.f), 10.f));
        float a1 = fabsf(fminf(fmaxf(v.y, -10.f), 10.f));
        mn0 = fminf(mn0, a0); mn1 = fminf(mn1, a1);
        s0 += a0; s1 += a1;
    }
    *(float2*)(pmin + blockIdx.x * NOUT + n2) = make_float2(mn0, mn1);
    *(float2*)(psum + blockIdx.x * NOUT + n2) = make_float2(s0, s1);
}

// ---- kB: fold partials -> scale[n], Gn[n]; + gumbel argmax -> eta4 ----
__global__ void kB_fold(const float* __restrict__ pmin, const float* __restrict__ psum,
                        const float* __restrict__ coeff, const float* __restrict__ gumb,
                        float* __restrict__ scale, float* __restrict__ Gn,
                        float4* __restrict__ eta4) {
    int n = threadIdx.x;  // 512
    float mn = 3.4e38f, s = 0.f;
    for (int i = 0; i < 64; i++) {
        mn = fminf(mn, pmin[i * NOUT + n]);
        s += psum[i * NOUT + n];
    }
    float sc = 1e-4f / mn;
    scale[n] = sc;
    Gn[n] = sc * s;
    float best = -1e30f;
    int bi = 0;
    for (int i = 0; i < 4; i++) {
        float c = fminf(fmaxf(coeff[i * NOUT + n], -1.f), 1.f);
        float u = gumb[i * NOUT + n];
        float g = -logf(-logf(u + 1e-20f) + 1e-20f);
        float v = c + g;
        if (v > best) { best = v; bi = i; }
    }
    eta4[n] = make_float4(c_etas[bi][0], c_etas[bi][1], c_etas[bi][2], c_etas[bi][3]);
}

// ---- kC: G[m] = sum_n g_init[m,n]*scale[n], one row per block (1 wave) ----
__global__ void kC_grow(const float* __restrict__ theta_, const float* __restrict__ scale,
                        float* __restrict__ G) {
    int m = blockIdx.x;
    int t = threadIdx.x;  // 64
    const float4* rowp = (const float4*)(theta_ + m * NOUT);
    const float4* scp = (const float4*)scale;
    float acc = 0.f;
#pragma unroll
    for (int i = 0; i < 2; i++) {
        float4 v = rowp[t * 2 + i];
        float4 s = scp[t * 2 + i];
        acc += fabsf(fminf(fmaxf(v.x, -10.f), 10.f)) * s.x
             + fabsf(fminf(fmaxf(v.y, -10.f), 10.f)) * s.y
             + fabsf(fminf(fmaxf(v.z, -10.f), 10.f)) * s.z
             + fabsf(fminf(fmaxf(v.w, -10.f), 10.f)) * s.w;
    }
    for (int off = 32; off > 0; off >>= 1) acc += __shfl_down(acc, off);
    if (t == 0) G[m] = acc;
}

// ---- k_wmat3 v3: B-matrices (RAW: Bz=th, Bt=sign*gi) + denom partials fused ----
__global__ void k_wmat3(const float* __restrict__ theta_, const float* __restrict__ noise,
                        u16* __restrict__ BzT, u16* __restrict__ BtT,
                        float* __restrict__ bias_z, float* __restrict__ bias_t,
                        float* __restrict__ denomp) {
    const int nt = blockIdx.x, mt = blockIdx.y, fv = blockIdx.z;  // 8,8,8
    const int t = threadIdx.x;
    const int nq = t & 15, mr = t >> 4;
    const int nb = nt * 64 + nq * 4;
    __shared__ u16 Wl[64][72];
    __shared__ u16 Sl[64][72];
    __shared__ float4 red[16][17];
    float4 dacc = {0.f, 0.f, 0.f, 0.f};
#pragma unroll
    for (int i = 0; i < 4; i++) {
        int ml = mr + i * 16;
        int m = mt * 64 + ml;
        float4 th4 = *(const float4*)(theta_ + m * NOUT + nb);
        float4 no4 = *(const float4*)(noise + (fv * NM + m) * NOUT + nb);
        ushort4 wv, sv;
#define WCOMP(c, fld) { float fac = no4.c * 0.2f + 0.9f; \
                        float thc = fminf(fmaxf(th4.c, -10.f), 10.f); \
                        float gi = fabsf(thc); \
                        float tht = (gi < 0.01f) ? 0.f : thc; \
                        float th = tht * fac; \
                        wv.fld = f2bf(th); \
                        sv.fld = f2bf((th >= 0.f) ? gi : -gi); \
                        dacc.c += fabsf(th); }
        WCOMP(x, x) WCOMP(y, y) WCOMP(z, z) WCOMP(w, w)
#undef WCOMP
        *(ushort4*)(&Wl[ml][nq * 4]) = wv;
        *(ushort4*)(&Sl[ml][nq * 4]) = sv;
    }
    red[mr][nq] = dacc;
    __syncthreads();
    if (t < 16) {
        float4 s = red[0][t];
#pragma unroll
        for (int r = 1; r < 16; r++) {
            float4 v = red[r][t];
            s.x += v.x; s.y += v.y; s.z += v.z; s.w += v.w;
        }
        *(float4*)(denomp + (mt * 8 + fv) * NOUT + nt * 64 + t * 4) = s;
    }
    // transposed write: thread -> 4 consecutive m (short4), n = t>>4 + 16r
    const int mb = (t & 15) * 4;
#pragma unroll
    for (int r = 0; r < 4; r++) {
        int nl = (t >> 4) + r * 16;
        ushort4 wv, sv;
        wv.x = Wl[mb][nl]; wv.y = Wl[mb + 1][nl]; wv.z = Wl[mb + 2][nl]; wv.w = Wl[mb + 3][nl];
        sv.x = Sl[mb][nl]; sv.y = Sl[mb + 1][nl]; sv.z = Sl[mb + 2][nl]; sv.w = Sl[mb + 3][nl];
        int gidx = (fv * NOUT + nt * 64 + nl) * NIN + mt * 64 + mb;
        *(ushort4*)(BzT + gidx) = wv;
        *(ushort4*)(BtT + gidx) = sv;
    }
    // bias row m=512 (raw th / raw sign*gi; scale+rdv applied in gemm epilogue)
    if (mt == 0 && t < 64) {
        int n = nt * 64 + t;
        float fac = noise[(fv * NM + 512) * NOUT + n] * 0.2f + 0.9f;
        float thc = fminf(fmaxf(theta_[512 * NOUT + n], -10.f), 10.f);
        float gi = fabsf(thc);
        float tht = (gi < 0.01f) ? 0.f : thc;
        float th = tht * fac;
        bias_z[fv * NOUT + n] = th;
        bias_t[fv * NOUT + n] = (th >= 0.f) ? gi : -gi;
    }
}

// ---- k_prepA: convert A to bf16 + p1 partial; spread atomic slots ----
__global__ void k_prepA(const float* __restrict__ a_prev, const float* __restrict__ G,
                        u16* __restrict__ Abf, float* __restrict__ p1slot) {
    int t = threadIdx.x;
    float acc = 0.f;
#pragma unroll
    for (int i = 0; i < 4; i++) {
        int idx = (i * 2048 + blockIdx.x) * 256 + t;
        float4 v = ((const float4*)a_prev)[idx];
        int k = (idx & 127) << 2;
        float4 g4 = *((const float4*)(G + k));
        acc += v.x * v.x * g4.x + v.y * v.y * g4.y + v.z * v.z * g4.z + v.w * v.w * g4.w;
        ushort4 o;
        o.x = f2bf(v.x); o.y = f2bf(v.y); o.z = f2bf(v.z); o.w = f2bf(v.w);
        ((ushort4*)Abf)[idx] = o;
    }
    for (int off = 32; off > 0; off >>= 1) acc += __shfl_down(acc, off);
    __shared__ float red[4];
    int lane = t & 63, wv = t >> 6;
    if (lane == 0) red[wv] = acc;
    __syncthreads();
    if (t == 0)
        atomicAdd(&p1slot[(blockIdx.x & 63) * 8], red[0] + red[1] + red[2] + red[3]);
}

// ---- k_gemm: dual-B MFMA GEMM + epilogue (denom fold via LDS) + last-block final ----
__global__ __launch_bounds__(256, 2) void k_gemm(
    const u16* __restrict__ Abf, const u16* __restrict__ BzT, const u16* __restrict__ BtT,
    const float* __restrict__ bias_z, const float* __restrict__ bias_t,
    const float* __restrict__ Gn, const float4* __restrict__ eta4,
    const float* __restrict__ theta_, const float* __restrict__ noise,
    const float* __restrict__ denomp, const float* __restrict__ scale,
    const float* __restrict__ G,
    float* __restrict__ out, float* __restrict__ p1slot,
    float* __restrict__ p2slot, float* __restrict__ p3slot,
    unsigned* __restrict__ ctr) {
    __shared__ alignas(16) u16 As[128 * 64];
    __shared__ alignas(16) u16 Bzs[128 * 64];
    __shared__ alignas(16) u16 Bts[128 * 64];
    const int tid = threadIdx.x;
    const int lane = tid & 63;
    const int wv = tid >> 6;
    const int wr = wv >> 1, wc = wv & 1;
    const int fv = blockIdx.z;
    const int e0 = blockIdx.y * 128;
    const int n0 = blockIdx.x * 128;

    const u16* Ag = Abf + (fv * NE + e0) * NIN;
    const u16* Bzg = BzT + (fv * NOUT + n0) * NIN;
    const u16* Btg = BtT + (fv * NOUT + n0) * NIN;

    f32x4 accz[4][4], acct[4][4];
#pragma unroll
    for (int i = 0; i < 4; i++)
#pragma unroll
        for (int j = 0; j < 4; j++) {
            f32x4 zz = {0.f, 0.f, 0.f, 0.f};
            accz[i][j] = zz;
            acct[i][j] = zz;
        }

    const int srow = tid >> 3;
    const int swz = (((tid & 7) ^ (srow & 7))) * 8;

    for (int k0 = 0; k0 < 512; k0 += 64) {
#pragma unroll
        for (int i = 0; i < 4; i++) {
            int so = (i * 32 + srow) * 512 + k0 + swz;
            int dof = i * 2048 + tid * 8;
            gll16(Ag + so, (u16*)As + dof);
            gll16(Bzg + so, (u16*)Bzs + dof);
            gll16(Btg + so, (u16*)Bts + dof);
        }
        __builtin_amdgcn_s_waitcnt(0);
        __syncthreads();
        const int rA = wr * 64 + (lane & 15);
        const int rB = wc * 64 + (lane & 15);
#pragma unroll
        for (int s = 0; s < 2; s++) {
            const int ca = ((s * 4 + (lane >> 4)) ^ (lane & 7)) * 8;
            short8 af[4], bzf[4], btf[4];
#pragma unroll
            for (int i = 0; i < 4; i++) af[i] = *(const short8*)(As + (rA + i * 16) * 64 + ca);
#pragma unroll
            for (int j = 0; j < 4; j++) {
                bzf[j] = *(const short8*)(Bzs + (rB + j * 16) * 64 + ca);
                btf[j] = *(const short8*)(Bts + (rB + j * 16) * 64 + ca);
            }
#pragma unroll
            for (int i = 0; i < 4; i++)
#pragma unroll
                for (int j = 0; j < 4; j++) {
                    accz[i][j] = __builtin_amdgcn_mfma_f32_16x16x32_bf16(af[i], bzf[j], accz[i][j], 0, 0, 0);
                    acct[i][j] = __builtin_amdgcn_mfma_f32_16x16x32_bf16(af[i], btf[j], acct[i][j], 0, 0, 0);
                }
        }
        __syncthreads();
    }

    // cooperative per-n epilogue constants (128 n per block) into LDS (reuse As)
    float* rdvl = (float*)As;
    float* bzl = rdvl + 128;
    float* btl = bzl + 128;
    float* gnl = btl + 128;
    float* scl = gnl + 128;
    float4* e4l = (float4*)(scl + 128);
    if (tid < 128) {
        int n = n0 + tid;
        float dsum = 1e-10f;
#pragma unroll
        for (int mc = 0; mc < 8; mc++) dsum += denomp[(mc * 8 + fv) * NOUT + n];
#pragma unroll
        for (int mx = 512; mx < 514; mx++) {
            float fac = noise[(fv * NM + mx) * NOUT + n] * 0.2f + 0.9f;
            float thc = fminf(fmaxf(theta_[mx * NOUT + n], -10.f), 10.f);
            float tht = (fabsf(thc) < 0.01f) ? 0.f : thc;
            dsum += fabsf(tht * fac);
        }
        rdvl[tid] = 1.f / dsum;
        bzl[tid] = bias_z[fv * NOUT + n];
        btl[tid] = bias_t[fv * NOUT + n];
        gnl[tid] = Gn[n];
        scl[tid] = scale[n];
        e4l[tid] = eta4[n];
    }
    __syncthreads();

    float p2 = 0.f, p3 = 0.f;
    const int col = lane & 15;
    const int rowq = (lane >> 4) * 4;
#pragma unroll
    for (int j = 0; j < 4; j++) {
        int nli = wc * 64 + j * 16 + col;
        int n = n0 + nli;
        float rdv = rdvl[nli];
        float bz = bzl[nli];
        float bt = btl[nli];
        float gnv = gnl[nli];
        float sc = scl[nli];
        float4 e4 = e4l[nli];
#pragma unroll
        for (int i = 0; i < 4; i++) {
            int ebase = e0 + wr * 64 + i * 16 + rowq;
#pragma unroll
            for (int r = 0; r < 4; r++) {
                float z = (accz[i][j][r] + bz) * rdv;
                float t = (acct[i][j][r] + bt) * sc;
                p2 += z * t;
                p3 += z * z * gnv;
                float x = (z - e4.z) * e4.w;
                float ex = __expf(2.f * x);
                float th = 1.f - 2.f / (ex + 1.f);
                out[(fv * NE + ebase + r) * NOUT + n] = e4.x + e4.y * th;
            }
        }
    }
    for (int off = 32; off > 0; off >>= 1) {
        p2 += __shfl_down(p2, off);
        p3 += __shfl_down(p3, off);
    }
    __shared__ float r2[4], r3[4];
    __shared__ unsigned lastf;
    if (lane == 0) { r2[wv] = p2; r3[wv] = p3; }
    __syncthreads();
    if (tid == 0) {
        int slot = ((blockIdx.x + blockIdx.y * 4 + blockIdx.z * 64) & 31) * 8;
        atomicAdd(&p2slot[slot], r2[0] + r2[1] + r2[2] + r2[3]);
        atomicAdd(&p3slot[slot], r3[0] + r3[1] + r3[2] + r3[3]);
        __threadfence();
        unsigned c = atomicAdd(ctr, 1u);
        lastf = (c == 511u) ? 1u : 0u;
    }
    __syncthreads();
    if (lastf && tid < 64) {
        __threadfence();
        float s1 = p1slot[tid * 8];
        float s2 = (tid < 32) ? p2slot[tid * 8] : 0.f;
        float s3 = (tid < 32) ? p3slot[tid * 8] : 0.f;
        for (int off = 32; off > 0; off >>= 1) {
            s1 += __shfl_down(s1, off);
            s2 += __shfl_down(s2, off);
            s3 += __shfl_down(s3, off);
        }
        if (tid == 0) {
            float mp = (s1 + 16384.f * G[512] - 2.f * s2 + s3) * (1.f / 16384.f);
            out[8388608] = mp;
        }
    }
}

extern "C" void kernel_launch(void* const* d_in, const int* in_sizes, int n_in,
                              void* d_out, int out_size, void* d_ws, size_t ws_size,
                              hipStream_t stream) {
    const float* a_prev = (const float*)d_in[0];
    const float* theta_ = (const float*)d_in[1];
    const float* coeff = (const float*)d_in[2];
    const float* noise = (const float*)d_in[3];
    const float* gumb = (const float*)d_in[4];
    float* out = (float*)d_out;
    char* w = (char*)d_ws;
    float* p1s = (float*)(w + WS_P1);
    float* p2s = (float*)(w + WS_P2);
    float* p3s = (float*)(w + WS_P3);
    unsigned* ctr = (unsigned*)(w + WS_CTR);
    float* scale = (float*)(w + WS_SCALE);
    float* G = (float*)(w + WS_G);
    float* Gn = (float*)(w + WS_GN);
    float4* eta4 = (float4*)(w + WS_ETA);
    float* bias_z = (float*)(w + WS_BIASZ);
    float* bias_t = (float*)(w + WS_BIAST);
    float* denomp = (float*)(w + WS_DENP);
    float* pmin = (float*)(w + WS_PMIN);
    float* psum = (float*)(w + WS_PSUM);
    u16* Abf = (u16*)(w + WS_ABF);
    u16* BzT = (u16*)(w + WS_BZT);
    u16* BtT = (u16*)(w + WS_BTT);

    kA_part<<<64, 256, 0, stream>>>(theta_, pmin, psum, (float*)w);
    kB_fold<<<1, 512, 0, stream>>>(pmin, psum, coeff, gumb, scale, Gn, eta4);
    kC_grow<<<514, 64, 0, stream>>>(theta_, scale, G);
    k_wmat3<<<dim3(8, 8, FV), 256, 0, stream>>>(theta_, noise, BzT, BtT,
                                                bias_z, bias_t, denomp);
    k_prepA<<<2048, 256, 0, stream>>>(a_prev, G, Abf, p1s);
    k_gemm<<<dim3(4, 16, FV), 256, 0, stream>>>(Abf, BzT, BtT, bias_z, bias_t, Gn, eta4,
                                                theta_, noise, denomp, scale, G,
                                                out, p1s, p2s, p3s, ctr);
}

// Round 10
// 138.714 us; speedup vs baseline: 1.1130x; 1.1130x over previous
//
#include <hip/hip_runtime.h>

typedef unsigned short u16;
typedef __attribute__((ext_vector_type(8))) short short8;
typedef __attribute__((ext_vector_type(4))) float f32x4;

#define NF 2
#define NV 4
#define FV 8
#define NE 2048
#define NIN 512
#define NOUT 512
#define NM 514

// ws layout (bytes)
#define WS_P1      0u         // 64 slots, stride 8 floats (32B)
#define WS_P2      2048u      // 32 slots * 32B
#define WS_P3      3072u      // 32 slots
#define WS_SCALE   4224u      // 512 f
#define WS_G       6272u      // 514 f (pad 2176)
#define WS_GN      8448u      // 512 f
#define WS_ETA     10496u     // 512 float4
#define WS_BIASZ   18688u     // 8*512 f (RAW th row 512)
#define WS_BIAST   35072u     // 8*512 f (sign*gi*scale row 512)
#define WS_DENP    51456u     // 8mt*8fv*512 f = 131072
#define WS_PMIN    182528u    // 64*512 f
#define WS_PSUM    313600u
#define WS_ABF     444672u    // 8*2048*512 u16
#define WS_BZT     17221888u  // 8*512*512 u16
#define WS_BTT     21416192u  // -> end 25610496

__constant__ float c_etas[4][4] = {
    {0.05f, 0.90f, 0.20f, 8.0f},
    {0.10f, 0.80f, 0.30f, 5.0f},
    {0.00f, 1.00f, 0.25f, 10.0f},
    {0.15f, 0.70f, 0.15f, 6.0f}};

__device__ __forceinline__ u16 f2bf(float x) {
    unsigned u = __float_as_uint(x);
    unsigned r = (u + 0x7fffu + ((u >> 16) & 1u)) >> 16;
    return (u16)r;
}

__device__ __forceinline__ void gll16(const void* g, void* l) {
    __builtin_amdgcn_global_load_lds((__attribute__((address_space(1))) void*)g,
                                     (__attribute__((address_space(3))) void*)l,
                                     16, 0, 0);
}

// ---- kA: per-column partial min/sum of g_init; block 0 zeroes slots ----
__global__ void kA_part(const float* __restrict__ theta_, float* __restrict__ pmin,
                        float* __restrict__ psum, float* __restrict__ wszero) {
    int t = threadIdx.x;
    if (blockIdx.x == 0) {
        for (int i = t; i < 1056; i += 256) wszero[i] = 0.f;
    }
    int n2 = t * 2;
    int r0 = blockIdx.x * 9;
    float mn0 = 3.4e38f, mn1 = 3.4e38f, s0 = 0.f, s1 = 0.f;
    int rend = r0 + 9;
    if (rend > NM) rend = NM;
    for (int r = r0; r < rend; r++) {
        float2 v = *(const float2*)(theta_ + r * NOUT + n2);
        float a0 = fabsf(fminf(fmaxf(v.x, -10.f), 10.f));
        float a1 = fabsf(fminf(fmaxf(v.y, -10.f), 10.f));
        mn0 = fminf(mn0, a0); mn1 = fminf(mn1, a1);
        s0 += a0; s1 += a1;
    }
    *(float2*)(pmin + blockIdx.x * NOUT + n2) = make_float2(mn0, mn1);
    *(float2*)(psum + blockIdx.x * NOUT + n2) = make_float2(s0, s1);
}

// ---- kB: fold partials -> scale[n], Gn[n]; + gumbel argmax -> eta4 ----
__global__ void kB_fold(const float* __restrict__ pmin, const float* __restrict__ psum,
                        const float* __restrict__ coeff, const float* __restrict__ gumb,
                        float* __restrict__ scale, float* __restrict__ Gn,
                        float4* __restrict__ eta4) {
    int n = threadIdx.x;  // 512
    float mn = 3.4e38f, s = 0.f;
    for (int i = 0; i < 64; i++) {
        mn = fminf(mn, pmin[i * NOUT + n]);
        s += psum[i * NOUT + n];
    }
    float sc = 1e-4f / mn;
    scale[n] = sc;
    Gn[n] = sc * s;
    float best = -1e30f;
    int bi = 0;
    for (int i = 0; i < 4; i++) {
        float c = fminf(fmaxf(coeff[i * NOUT + n], -1.f), 1.f);
        float u = gumb[i * NOUT + n];
        float g = -logf(-logf(u + 1e-20f) + 1e-20f);
        float v = c + g;
        if (v > best) { best = v; bi = i; }
    }
    eta4[n] = make_float4(c_etas[bi][0], c_etas[bi][1], c_etas[bi][2], c_etas[bi][3]);
}

// ---- kC: G[m] = sum_n g_init[m,n]*scale[n], one row per block (1 wave) ----
__global__ void kC_grow(const float* __restrict__ theta_, const float* __restrict__ scale,
                        float* __restrict__ G) {
    int m = blockIdx.x;
    int t = threadIdx.x;  // 64
    const float4* rowp = (const float4*)(theta_ + m * NOUT);
    const float4* scp = (const float4*)scale;
    float acc = 0.f;
#pragma unroll
    for (int i = 0; i < 2; i++) {
        float4 v = rowp[t * 2 + i];
        float4 s = scp[t * 2 + i];
        acc += fabsf(fminf(fmaxf(v.x, -10.f), 10.f)) * s.x
             + fabsf(fminf(fmaxf(v.y, -10.f), 10.f)) * s.y
             + fabsf(fminf(fmaxf(v.z, -10.f), 10.f)) * s.z
             + fabsf(fminf(fmaxf(v.w, -10.f), 10.f)) * s.w;
    }
    for (int off = 32; off > 0; off >>= 1) acc += __shfl_down(acc, off);
    if (t == 0) G[m] = acc;
}

// ---- k_wmat3: B-matrices (Bz=raw th, Bt=sign*gi*scale) + denom partials fused ----
__global__ void k_wmat3(const float* __restrict__ theta_, const float* __restrict__ scale,
                        const float* __restrict__ noise,
                        u16* __restrict__ BzT, u16* __restrict__ BtT,
                        float* __restrict__ bias_z, float* __restrict__ bias_t,
                        float* __restrict__ denomp) {
    const int nt = blockIdx.x, mt = blockIdx.y, fv = blockIdx.z;  // 8,8,8
    const int t = threadIdx.x;
    const int nq = t & 15, mr = t >> 4;
    const int nb = nt * 64 + nq * 4;
    __shared__ u16 Wl[64][72];
    __shared__ u16 Sl[64][72];
    __shared__ float4 red[16][17];
    float4 sc4 = *(const float4*)(scale + nb);
    float4 dacc = {0.f, 0.f, 0.f, 0.f};
#pragma unroll
    for (int i = 0; i < 4; i++) {
        int ml = mr + i * 16;
        int m = mt * 64 + ml;
        float4 th4 = *(const float4*)(theta_ + m * NOUT + nb);
        float4 no4 = *(const float4*)(noise + (fv * NM + m) * NOUT + nb);
        ushort4 wv, sv;
#define WCOMP(c, fld) { float fac = no4.c * 0.2f + 0.9f; \
                        float thc = fminf(fmaxf(th4.c, -10.f), 10.f); \
                        float gi = fabsf(thc); \
                        float tht = (gi < 0.01f) ? 0.f : thc; \
                        float th = tht * fac; \
                        wv.fld = f2bf(th); \
                        sv.fld = f2bf(((th >= 0.f) ? gi : -gi) * sc4.c); \
                        dacc.c += fabsf(th); }
        WCOMP(x, x) WCOMP(y, y) WCOMP(z, z) WCOMP(w, w)
#undef WCOMP
        *(ushort4*)(&Wl[ml][nq * 4]) = wv;
        *(ushort4*)(&Sl[ml][nq * 4]) = sv;
    }
    red[mr][nq] = dacc;
    __syncthreads();
    if (t < 16) {
        float4 s = red[0][t];
#pragma unroll
        for (int r = 1; r < 16; r++) {
            float4 v = red[r][t];
            s.x += v.x; s.y += v.y; s.z += v.z; s.w += v.w;
        }
        *(float4*)(denomp + (mt * 8 + fv) * NOUT + nt * 64 + t * 4) = s;
    }
    const int mb = (t & 15) * 4;
#pragma unroll
    for (int r = 0; r < 4; r++) {
        int nl = (t >> 4) + r * 16;
        ushort4 wv, sv;
        wv.x = Wl[mb][nl]; wv.y = Wl[mb + 1][nl]; wv.z = Wl[mb + 2][nl]; wv.w = Wl[mb + 3][nl];
        sv.x = Sl[mb][nl]; sv.y = Sl[mb + 1][nl]; sv.z = Sl[mb + 2][nl]; sv.w = Sl[mb + 3][nl];
        int gidx = (fv * NOUT + nt * 64 + nl) * NIN + mt * 64 + mb;
        *(ushort4*)(BzT + gidx) = wv;
        *(ushort4*)(BtT + gidx) = sv;
    }
    if (mt == 0 && t < 64) {
        int n = nt * 64 + t;
        float fac = noise[(fv * NM + 512) * NOUT + n] * 0.2f + 0.9f;
        float thc = fminf(fmaxf(theta_[512 * NOUT + n], -10.f), 10.f);
        float gi = fabsf(thc);
        float tht = (gi < 0.01f) ? 0.f : thc;
        float th = tht * fac;
        bias_z[fv * NOUT + n] = th;
        bias_t[fv * NOUT + n] = ((th >= 0.f) ? gi : -gi) * scale[n];
    }
}

// ---- k_prepA: convert A to bf16 + p1 partial; spread atomic slots ----
__global__ void k_prepA(const float* __restrict__ a_prev, const float* __restrict__ G,
                        u16* __restrict__ Abf, float* __restrict__ p1slot) {
    int t = threadIdx.x;
    float acc = 0.f;
#pragma unroll
    for (int i = 0; i < 4; i++) {
        int idx = (i * 2048 + blockIdx.x) * 256 + t;
        float4 v = ((const float4*)a_prev)[idx];
        int k = (idx & 127) << 2;
        float4 g4 = *((const float4*)(G + k));
        acc += v.x * v.x * g4.x + v.y * v.y * g4.y + v.z * v.z * g4.z + v.w * v.w * g4.w;
        ushort4 o;
        o.x = f2bf(v.x); o.y = f2bf(v.y); o.z = f2bf(v.z); o.w = f2bf(v.w);
        ((ushort4*)Abf)[idx] = o;
    }
    for (int off = 32; off > 0; off >>= 1) acc += __shfl_down(acc, off);
    __shared__ float red[4];
    int lane = t & 63, wv = t >> 6;
    if (lane == 0) red[wv] = acc;
    __syncthreads();
    if (t == 0)
        atomicAdd(&p1slot[(blockIdx.x & 63) * 8], red[0] + red[1] + red[2] + red[3]);
}

// ---- k_gemm: dual-B MFMA GEMM, R8 epilogue, XCD-locality swizzle ----
// 1-D grid of 512; fv = b&7 so (assuming round-robin workgroup->XCD) all 64
// blocks of one fv land on one XCD -> its A slice (2 MB) + B (1 MB) stay in
// that XCD's 4 MB L2. Heuristic only: any mapping is correct.
__global__ __launch_bounds__(256, 2) void k_gemm(
    const u16* __restrict__ Abf, const u16* __restrict__ BzT, const u16* __restrict__ BtT,
    const float* __restrict__ bias_z, const float* __restrict__ bias_t,
    const float* __restrict__ Gn, const float4* __restrict__ eta4,
    const float* __restrict__ theta_, const float* __restrict__ noise,
    const float* __restrict__ denomp,
    float* __restrict__ out, float* __restrict__ p2slot, float* __restrict__ p3slot) {
    __shared__ alignas(16) u16 As[128 * 64];
    __shared__ alignas(16) u16 Bzs[128 * 64];
    __shared__ alignas(16) u16 Bts[128 * 64];
    const int tid = threadIdx.x;
    const int lane = tid & 63;
    const int wv = tid >> 6;
    const int wr = wv >> 1, wc = wv & 1;
    const int b = blockIdx.x;
    const int fv = b & 7;
    const int kk = b >> 3;
    const int n0 = (kk & 3) * 128;
    const int e0 = (kk >> 2) * 128;

    const u16* Ag = Abf + (fv * NE + e0) * NIN;
    const u16* Bzg = BzT + (fv * NOUT + n0) * NIN;
    const u16* Btg = BtT + (fv * NOUT + n0) * NIN;

    f32x4 accz[4][4], acct[4][4];
#pragma unroll
    for (int i = 0; i < 4; i++)
#pragma unroll
        for (int j = 0; j < 4; j++) {
            f32x4 zz = {0.f, 0.f, 0.f, 0.f};
            accz[i][j] = zz;
            acct[i][j] = zz;
        }

    const int srow = tid >> 3;
    const int swz = (((tid & 7) ^ (srow & 7))) * 8;

    for (int k0 = 0; k0 < 512; k0 += 64) {
#pragma unroll
        for (int i = 0; i < 4; i++) {
            int so = (i * 32 + srow) * 512 + k0 + swz;
            int dof = i * 2048 + tid * 8;
            gll16(Ag + so, (u16*)As + dof);
            gll16(Bzg + so, (u16*)Bzs + dof);
            gll16(Btg + so, (u16*)Bts + dof);
        }
        __builtin_amdgcn_s_waitcnt(0);
        __syncthreads();
        const int rA = wr * 64 + (lane & 15);
        const int rB = wc * 64 + (lane & 15);
#pragma unroll
        for (int s = 0; s < 2; s++) {
            const int ca = ((s * 4 + (lane >> 4)) ^ (lane & 7)) * 8;
            short8 af[4], bzf[4], btf[4];
#pragma unroll
            for (int i = 0; i < 4; i++) af[i] = *(const short8*)(As + (rA + i * 16) * 64 + ca);
#pragma unroll
            for (int j = 0; j < 4; j++) {
                bzf[j] = *(const short8*)(Bzs + (rB + j * 16) * 64 + ca);
                btf[j] = *(const short8*)(Bts + (rB + j * 16) * 64 + ca);
            }
#pragma unroll
            for (int i = 0; i < 4; i++)
#pragma unroll
                for (int j = 0; j < 4; j++) {
                    accz[i][j] = __builtin_amdgcn_mfma_f32_16x16x32_bf16(af[i], bzf[j], accz[i][j], 0, 0, 0);
                    acct[i][j] = __builtin_amdgcn_mfma_f32_16x16x32_bf16(af[i], btf[j], acct[i][j], 0, 0, 0);
                }
        }
        __syncthreads();
    }

    float p2 = 0.f, p3 = 0.f;
    const int col = lane & 15;
    const int rowq = (lane >> 4) * 4;
#pragma unroll
    for (int j = 0; j < 4; j++) {
        int n = n0 + wc * 64 + j * 16 + col;
        float dsum = 1e-10f;
#pragma unroll
        for (int mc = 0; mc < 8; mc++) dsum += denomp[(mc * 8 + fv) * NOUT + n];
#pragma unroll
        for (int mx = 512; mx < 514; mx++) {
            float fac = noise[(fv * NM + mx) * NOUT + n] * 0.2f + 0.9f;
            float thc = fminf(fmaxf(theta_[mx * NOUT + n], -10.f), 10.f);
            float tht = (fabsf(thc) < 0.01f) ? 0.f : thc;
            dsum += fabsf(tht * fac);
        }
        float rdv = 1.f / dsum;
        float bz = bias_z[fv * NOUT + n];
        float bt = bias_t[fv * NOUT + n];
        float gnv = Gn[n];
        float4 e4 = eta4[n];
#pragma unroll
        for (int i = 0; i < 4; i++) {
            int ebase = e0 + wr * 64 + i * 16 + rowq;
#pragma unroll
            for (int r = 0; r < 4; r++) {
                float z = (accz[i][j][r] + bz) * rdv;
                float t = acct[i][j][r] + bt;
                p2 += z * t;
                p3 += z * z * gnv;
                float x = (z - e4.z) * e4.w;
                float ex = __expf(2.f * x);
                float th = 1.f - 2.f / (ex + 1.f);
                out[(fv * NE + ebase + r) * NOUT + n] = e4.x + e4.y * th;
            }
        }
    }
    for (int off = 32; off > 0; off >>= 1) {
        p2 += __shfl_down(p2, off);
        p3 += __shfl_down(p3, off);
    }
    __shared__ float r2[4], r3[4];
    if (lane == 0) { r2[wv] = p2; r3[wv] = p3; }
    __syncthreads();
    if (tid == 0) {
        int slot = (b & 31) * 8;
        atomicAdd(&p2slot[slot], r2[0] + r2[1] + r2[2] + r2[3]);
        atomicAdd(&p3slot[slot], r3[0] + r3[1] + r3[2] + r3[3]);
    }
}

// ---- k_final: sum slots, combine power terms ----
__global__ void k_final(const float* __restrict__ p1s, const float* __restrict__ p2s,
                        const float* __restrict__ p3s, const float* __restrict__ G,
                        float* __restrict__ out) {
    int t = threadIdx.x;  // 64
    float s1 = p1s[t * 8];
    float s2 = (t < 32) ? p2s[t * 8] : 0.f;
    float s3 = (t < 32) ? p3s[t * 8] : 0.f;
    for (int off = 32; off > 0; off >>= 1) {
        s1 += __shfl_down(s1, off);
        s2 += __shfl_down(s2, off);
        s3 += __shfl_down(s3, off);
    }
    if (t == 0) {
        float mp = (s1 + 16384.f * G[512] - 2.f * s2 + s3) * (1.f / 16384.f);
        out[8388608] = mp;
    }
}

extern "C" void kernel_launch(void* const* d_in, const int* in_sizes, int n_in,
                              void* d_out, int out_size, void* d_ws, size_t ws_size,
                              hipStream_t stream) {
    const float* a_prev = (const float*)d_in[0];
    const float* theta_ = (const float*)d_in[1];
    const float* coeff = (const float*)d_in[2];
    const float* noise = (const float*)d_in[3];
    const float* gumb = (const float*)d_in[4];
    float* out = (float*)d_out;
    char* w = (char*)d_ws;
    float* p1s = (float*)(w + WS_P1);
    float* p2s = (float*)(w + WS_P2);
    float* p3s = (float*)(w + WS_P3);
    float* scale = (float*)(w + WS_SCALE);
    float* G = (float*)(w + WS_G);
    float* Gn = (float*)(w + WS_GN);
    float4* eta4 = (float4*)(w + WS_ETA);
    float* bias_z = (float*)(w + WS_BIASZ);
    float* bias_t = (float*)(w + WS_BIAST);
    float* denomp = (float*)(w + WS_DENP);
    float* pmin = (float*)(w + WS_PMIN);
    float* psum = (float*)(w + WS_PSUM);
    u16* Abf = (u16*)(w + WS_ABF);
    u16* BzT = (u16*)(w + WS_BZT);
    u16* BtT = (u16*)(w + WS_BTT);

    kA_part<<<64, 256, 0, stream>>>(theta_, pmin, psum, (float*)w);
    kB_fold<<<1, 512, 0, stream>>>(pmin, psum, coeff, gumb, scale, Gn, eta4);
    kC_grow<<<514, 64, 0, stream>>>(theta_, scale, G);
    k_wmat3<<<dim3(8, 8, FV), 256, 0, stream>>>(theta_, scale, noise, BzT, BtT,
                                                bias_z, bias_t, denomp);
    k_prepA<<<2048, 256, 0, stream>>>(a_prev, G, Abf, p1s);
    k_gemm<<<512, 256, 0, stream>>>(Abf, BzT, BtT, bias_z, bias_t, Gn, eta4,
                                    theta_, noise, denomp, out, p2s, p3s);
    k_final<<<1, 64, 0, stream>>>(p1s, p2s, p3s, G, out);
}